// Round 7
// baseline (963.752 us; speedup 1.0000x reference)
//
#include <hip/hip_runtime.h>
#include <hip/hip_bf16.h>
#include <stdint.h>

#define KTOT 8192
#define BM 64
#define BK 128
#define KSPLIT 4
#define KCHUNK (KTOT / KSPLIT)   // 2048
#define NIT (KCHUNK / BK)        // 16
#define NB 256                   // persistent grid: 1 block/CU

typedef __attribute__((ext_vector_type(8))) __bf16 bf16x8;
typedef __attribute__((ext_vector_type(4))) float f32x4;

__device__ __forceinline__ unsigned short f2bf(float f) {
  union { float f; unsigned int u; } a;
  a.f = f;
  unsigned int r = (a.u + 0x7fffu + ((a.u >> 16) & 1u)) >> 16;
  return (unsigned short)r;
}

__device__ __forceinline__ uint2 pack4(f32x4 v) {
  union { unsigned short h[4]; uint2 u; } pk;
  pk.h[0] = f2bf(v[0]); pk.h[1] = f2bf(v[1]);
  pk.h[2] = f2bf(v[2]); pk.h[3] = f2bf(v[3]);
  return pk.u;
}

// Sense-free generation barrier. cnt/gen zeroed by bar_init each launch.
__device__ __forceinline__ void grid_barrier(unsigned* cnt, unsigned* gen) {
  __syncthreads();
  __threadfence();
  if (threadIdx.x == 0) {
    unsigned g = __hip_atomic_load(gen, __ATOMIC_ACQUIRE, __HIP_MEMORY_SCOPE_AGENT);
    unsigned a = __hip_atomic_fetch_add(cnt, 1u, __ATOMIC_ACQ_REL,
                                        __HIP_MEMORY_SCOPE_AGENT) + 1u;
    if (a == NB) {
      __hip_atomic_store(cnt, 0u, __ATOMIC_RELAXED, __HIP_MEMORY_SCOPE_AGENT);
      __hip_atomic_fetch_add(gen, 1u, __ATOMIC_RELEASE, __HIP_MEMORY_SCOPE_AGENT);
    } else {
      while (__hip_atomic_load(gen, __ATOMIC_ACQUIRE, __HIP_MEMORY_SCOPE_AGENT) == g)
        __builtin_amdgcn_s_sleep(2);
    }
  }
  __threadfence();
  __syncthreads();
}

__global__ void bar_init(unsigned* bar) {
  if (threadIdx.x < 2) bar[threadIdx.x] = 0;
}

// x [8192][64] f32 tile r0..r0+63 -> xt [64][8192] bf16 (transposed). 512 thr.
__device__ void d_xpose(const float* __restrict__ x, unsigned short* __restrict__ xt,
                        int r0, int t, unsigned char* smem) {
  unsigned short(*tile)[72] = (unsigned short(*)[72])smem;
  const int a = t >> 4;          // 0..31
  const int c4 = (t & 15) * 4;   // 0..60
#pragma unroll
  for (int rep = 0; rep < 2; ++rep) {
    int r = a + rep * 32;
    f32x4 v = __builtin_nontemporal_load(
        reinterpret_cast<const f32x4*>(x + (size_t)(r0 + r) * 64 + c4));
    tile[c4 + 0][r] = f2bf(v[0]);
    tile[c4 + 1][r] = f2bf(v[1]);
    tile[c4 + 2][r] = f2bf(v[2]);
    tile[c4 + 3][r] = f2bf(v[3]);
  }
  __syncthreads();
#pragma unroll
  for (int rep = 0; rep < 2; ++rep) {
    int j = a + rep * 32;
    uint2 v = *reinterpret_cast<const uint2*>(&tile[j][c4]);
    *reinterpret_cast<uint2*>(xt + (size_t)j * KTOT + r0 + c4) = v;
  }
}

// One (mblk, kc) GEMM work item: part[kc][col][r0..r0+63] = A-slice @ B.
// A f32 reg->bf16->LDS (XOR swizzle), depth-2 prefetch; B bf16 direct from
// global (L2-hot) into regs. 8 waves, wave w owns cols w*16..+15, 4 M-tiles.
__device__ void d_gemm(const float* __restrict__ A,
                       const unsigned short* __restrict__ BT,
                       float* __restrict__ part, int mblk, int kc, int t,
                       unsigned char* smem) {
  constexpr int SZ_A = BM * BK * 2;   // 16 KiB
  const int r0 = mblk * BM;
  const int kbase = kc * KCHUNK;
  const int l = t & 63;
  const int w = t >> 6;

  const float* aptr[4];
  int loff_a[4];
#pragma unroll
  for (int r = 0; r < 4; ++r) {
    int idx = t + r * 512;
    int m = idx >> 5, c4 = idx & 31;
    aptr[r] = A + (size_t)(r0 + m) * KTOT + kbase + c4 * 4;
    loff_a[r] = m * 256 + ((c4 * 8) ^ ((m & 7) << 4));
  }

  const int lr = l & 15;
  const int g = l >> 4;
  const int col = w * 16 + lr;
  const unsigned short* bptr = BT + (size_t)col * KTOT + kbase + g * 8;
  const int asw = (lr & 7) << 4;

  f32x4 acc[4];
  const f32x4 fzero = {0.f, 0.f, 0.f, 0.f};
#pragma unroll
  for (int mt = 0; mt < 4; ++mt) acc[mt] = fzero;

  f32x4 av0[4], av1[4];
  bf16x8 Bf0[4], Bf1[4];
  unsigned char* lds0 = smem;
  unsigned char* lds1 = smem + SZ_A;

#define LOAD_A(AV, K0)                                                        \
  _Pragma("unroll") for (int r = 0; r < 4; ++r)                               \
      AV[r] = __builtin_nontemporal_load(                                     \
          reinterpret_cast<const f32x4*>(aptr[r] + (K0)));
#define LOAD_B(BF, K0)                                                        \
  _Pragma("unroll") for (int ks = 0; ks < 4; ++ks)                            \
      BF[ks] = *reinterpret_cast<const bf16x8*>(bptr + (K0) + ks * 32);
#define WRITE_A(LDS, AV)                                                      \
  _Pragma("unroll") for (int r = 0; r < 4; ++r) {                             \
    *reinterpret_cast<uint2*>((LDS) + loff_a[r]) = pack4(AV[r]);              \
  }
#define COMPUTE(LDS, BF)                                                      \
  _Pragma("unroll") for (int ks = 0; ks < 4; ++ks) {                          \
    _Pragma("unroll") for (int mt = 0; mt < 4; ++mt) {                        \
      bf16x8 af_ = *reinterpret_cast<const bf16x8*>(                          \
          (LDS) + (mt * 16 + lr) * 256 + ((ks * 64 + g * 16) ^ asw));         \
      acc[mt] = __builtin_amdgcn_mfma_f32_16x16x32_bf16(af_, BF[ks], acc[mt], \
                                                        0, 0, 0);             \
    }                                                                         \
  }

  LOAD_A(av0, 0); LOAD_B(Bf0, 0);
  LOAD_A(av1, BK); LOAD_B(Bf1, BK);
  WRITE_A(lds0, av0);
  __syncthreads();

#pragma unroll 1
  for (int it = 0; it < NIT; it += 2) {
    if (it + 2 < NIT) { LOAD_A(av0, (it + 2) * BK); }
    COMPUTE(lds0, Bf0);
    if (it + 2 < NIT) { LOAD_B(Bf0, (it + 2) * BK); }
    if (it + 1 < NIT) { WRITE_A(lds1, av1); }
    __syncthreads();
    if (it + 3 < NIT) { LOAD_A(av1, (it + 3) * BK); }
    if (it + 1 < NIT) { COMPUTE(lds1, Bf1); }
    if (it + 3 < NIT) { LOAD_B(Bf1, (it + 3) * BK); }
    if (it + 2 < NIT) { WRITE_A(lds0, av0); }
    __syncthreads();
  }

  float* pp = part + (size_t)(kc * 128 + col) * KTOT + r0 + g * 4;
#pragma unroll
  for (int mt = 0; mt < 4; ++mt)
    __builtin_nontemporal_store(acc[mt], reinterpret_cast<f32x4*>(pp + mt * 16));
#undef LOAD_A
#undef LOAD_B
#undef WRITE_A
#undef COMPUTE
}

// Combine KSPLIT partials + epilogue, separate halves. 512 thr x 32 rows/block.
__device__ void d_reduce_sep(const float* __restrict__ part, float* __restrict__ out,
                             const float* s_lo_p, const float* s_hi_p,
                             const float* __restrict__ add_ptr, const float* add_s_p,
                             unsigned short* bt_lo, unsigned short* bt_hi,
                             int base_lo, int base_hi, int accum, int b, int t) {
  const int col = t & 127;
  const int rbase = b * 32 + (t >> 7) * 8;
  const float* p0 = part + (size_t)col * KTOT + rbase;
  const bool hi = col >= 64;
  const int col64 = hi ? col - 64 : col;
  unsigned short* bt = hi ? bt_hi : bt_lo;
  const int obase = hi ? base_hi : base_lo;
  const float s = hi ? (s_hi_p ? *s_hi_p : 0.f) : (s_lo_p ? *s_lo_p : 0.f);
  const float was = add_s_p ? *add_s_p : 0.f;
#pragma unroll
  for (int i = 0; i < 2; ++i) {
    f32x4 c = __builtin_nontemporal_load(
        reinterpret_cast<const f32x4*>(p0 + 4 * i));
#pragma unroll
    for (int k = 1; k < KSPLIT; ++k)
      c += __builtin_nontemporal_load(reinterpret_cast<const f32x4*>(
          p0 + (size_t)k * 128 * KTOT + 4 * i));
    if (bt)
      *reinterpret_cast<uint2*>(bt + (size_t)col64 * KTOT + rbase + 4 * i) = pack4(c);
    if (obase >= 0) {
#pragma unroll
      for (int j = 0; j < 4; ++j) {
        int row = rbase + 4 * i + j;
        float v = s * c[j];
        if (add_ptr && !hi) v = fmaf(was, add_ptr[(size_t)row * 64 + col64], v);
        if (accum) v += out[(size_t)row * 128 + obase + col64];
        out[(size_t)row * 128 + obase + col64] = v;
      }
    }
  }
}

// Combine partials + cross-half epilogue: out[:,64+c] = sl*lo[c] + sh*hi[c];
// bt_lo = raw lo (bf16 transposed). 512 thr x 32 rows/block.
__device__ void d_reduce_comb(const float* __restrict__ part, float* __restrict__ out,
                              const float* s_lo_p, const float* s_hi_p,
                              unsigned short* bt_lo, int b, int t) {
  const int c = t & 63;
  const int rbase = b * 32 + (t >> 6) * 4;
  const float* pl = part + (size_t)c * KTOT + rbase;
  const float* ph = part + (size_t)(c + 64) * KTOT + rbase;
  const float sl = *s_lo_p, sh = *s_hi_p;
  f32x4 lo = __builtin_nontemporal_load(reinterpret_cast<const f32x4*>(pl));
  f32x4 hv = __builtin_nontemporal_load(reinterpret_cast<const f32x4*>(ph));
#pragma unroll
  for (int k = 1; k < KSPLIT; ++k) {
    lo += __builtin_nontemporal_load(
        reinterpret_cast<const f32x4*>(pl + (size_t)k * 128 * KTOT));
    hv += __builtin_nontemporal_load(
        reinterpret_cast<const f32x4*>(ph + (size_t)k * 128 * KTOT));
  }
  *reinterpret_cast<uint2*>(bt_lo + (size_t)c * KTOT + rbase) = pack4(lo);
#pragma unroll
  for (int j = 0; j < 4; ++j) {
    int row = rbase + j;
    out[(size_t)row * 128 + 64 + c] = sl * lo[j] + sh * hv[j];
  }
}

__global__ __launch_bounds__(512, 4) void simpa_fused(
    const float* __restrict__ A_p, const float* __restrict__ A_n,
    const float* __restrict__ x_p, const float* __restrict__ x_n,
    const float* __restrict__ w_p, const float* __restrict__ w_n,
    float* __restrict__ out, unsigned short* BTbig, unsigned short* B3T,
    float* part, unsigned* bar) {
  __shared__ __align__(16) unsigned char smem[2 * BM * BK * 2];  // 32 KiB
  const int b = blockIdx.x;
  const int t = threadIdx.x;

  // XCD-affine work split: both gemm items of a block share kc (B L2-hot).
  const int kc = (b & 7) >> 1;
  const int mb0 = ((b >> 3) << 1) | (b & 1);   // 0..63

  // phase 0: transpose x_p, x_n -> BTbig rows 0-63 / 64-127
  if (b < 128) d_xpose(x_p, BTbig, b * 64, t, smem);
  else d_xpose(x_n, BTbig + (size_t)64 * KTOT, (b - 128) * 64, t, smem);
  grid_barrier(bar, bar + 1);

  // phase 1: G1 = A_p @ [x_p|x_n]
  d_gemm(A_p, BTbig, part, mb0, kc, t, smem);
  __syncthreads();
  d_gemm(A_p, BTbig, part, mb0 + 64, kc, t, smem);
  grid_barrier(bar, bar + 1);

  // phase 2: out[:,0:64] = wp0*x_p + wp1*P1; emit P1^T -> B3T[0:64],
  //          Y1^T -> BTbig[128:192]
  d_reduce_sep(part, out, w_p + 1, nullptr, x_p, w_p + 0,
               B3T, BTbig + (size_t)128 * KTOT, 0, -1, 0, b, t);
  grid_barrier(bar, bar + 1);

  // phase 3: G2' = A_n @ [x_n|Y1]
  d_gemm(A_n, BTbig + (size_t)64 * KTOT, part, mb0, kc, t, smem);
  __syncthreads();
  d_gemm(A_n, BTbig + (size_t)64 * KTOT, part, mb0 + 64, kc, t, smem);
  grid_barrier(bar, bar + 1);

  // phase 4: out[:,64:128] = wn0*T1 + wn2*T3; emit T1^T -> B3T[64:128]
  d_reduce_comb(part, out, w_n + 0, w_n + 2, B3T + (size_t)64 * KTOT, b, t);
  grid_barrier(bar, bar + 1);

  // phase 5: G3 = A_p @ [P1|T1]
  d_gemm(A_p, B3T, part, mb0, kc, t, smem);
  __syncthreads();
  d_gemm(A_p, B3T, part, mb0 + 64, kc, t, smem);
  grid_barrier(bar, bar + 1);

  // phase 6: out[:,0:64] += wp2*P2; out[:,64:128] += wn1*T2
  d_reduce_sep(part, out, w_p + 2, w_n + 1, nullptr, nullptr,
               nullptr, nullptr, 0, 64, 1, b, t);
}

extern "C" void kernel_launch(void* const* d_in, const int* in_sizes, int n_in,
                              void* d_out, int out_size, void* d_ws, size_t ws_size,
                              hipStream_t stream) {
  const float* A_p = (const float*)d_in[0];
  const float* A_n = (const float*)d_in[1];
  const float* x_p = (const float*)d_in[2];
  const float* x_n = (const float*)d_in[3];
  const float* w_p = (const float*)d_in[4];  // [3]
  const float* w_n = (const float*)d_in[5];  // [3]
  float* out = (float*)d_out;                // [8192][128]

  // ws layout (21 MiB + 8 B):
  //   BTbig [192][8192] bf16: rows 0-63 x_p^T, 64-127 x_n^T, 128-191 Y1^T
  //   B3T   [128][8192] bf16: rows 0-63 P1^T, 64-127 T1^T
  //   part  [KSPLIT][128][8192] f32
  //   bar   [2] u32 (grid barrier state)
  unsigned short* BTbig = (unsigned short*)d_ws;
  unsigned short* B3T = BTbig + (size_t)192 * KTOT;
  float* part = (float*)(B3T + (size_t)128 * KTOT);
  unsigned* bar = (unsigned*)(part + (size_t)KSPLIT * 128 * KTOT);

  bar_init<<<1, 64, 0, stream>>>(bar);
  simpa_fused<<<NB, 512, 0, stream>>>(A_p, A_n, x_p, x_n, w_p, w_n, out,
                                      BTbig, B3T, part, bar);
}

// Round 8
// 468.229 us; speedup vs baseline: 2.0583x; 2.0583x over previous
//
#include <hip/hip_runtime.h>
#include <hip/hip_bf16.h>
#include <stdint.h>

#define KTOT 8192
#define BM 64
#define BK 128
#define KSPLIT 4
#define KCHUNK (KTOT / KSPLIT)   // 2048
#define NIT (KCHUNK / BK)        // 16

typedef __attribute__((ext_vector_type(8))) __bf16 bf16x8;
typedef __attribute__((ext_vector_type(4))) float f32x4;

__device__ __forceinline__ unsigned short f2bf(float f) {
  union { float f; unsigned int u; } a;
  a.f = f;
  unsigned int r = (a.u + 0x7fffu + ((a.u >> 16) & 1u)) >> 16;
  return (unsigned short)r;
}

__device__ __forceinline__ uint2 pack4(f32x4 v) {
  union { unsigned short h[4]; uint2 u; } pk;
  pk.h[0] = f2bf(v[0]); pk.h[1] = f2bf(v[1]);
  pk.h[2] = f2bf(v[2]); pk.h[3] = f2bf(v[3]);
  return pk.u;
}

// Barrier that drains LDS only — global prefetches stay in flight (T4).
__device__ __forceinline__ void block_bar() {
  asm volatile("s_waitcnt lgkmcnt(0)" ::: "memory");
  __builtin_amdgcn_s_barrier();
  __builtin_amdgcn_sched_barrier(0);
}

// x [8192][64] f32  ->  xt [64][8192] bf16 (transposed)
__global__ __launch_bounds__(256) void xpose_f32_bf16(const float* __restrict__ x,
                                                      __hip_bfloat16* __restrict__ xt) {
  __shared__ unsigned short tile[64][72];
  const int r0 = blockIdx.x * 64;
  const int t = threadIdx.x;
  const int a = t >> 4;
  const int c4 = (t & 15) * 4;
#pragma unroll
  for (int rep = 0; rep < 4; ++rep) {
    int r = a + rep * 16;
    f32x4 v = __builtin_nontemporal_load(
        reinterpret_cast<const f32x4*>(x + (size_t)(r0 + r) * 64 + c4));
    tile[c4 + 0][r] = f2bf(v[0]);
    tile[c4 + 1][r] = f2bf(v[1]);
    tile[c4 + 2][r] = f2bf(v[2]);
    tile[c4 + 3][r] = f2bf(v[3]);
  }
  __syncthreads();
#pragma unroll
  for (int rep = 0; rep < 4; ++rep) {
    int j = a + rep * 16;
    uint2 v = *reinterpret_cast<const uint2*>(&tile[j][c4]);
    *reinterpret_cast<uint2*>((unsigned short*)xt + (size_t)j * KTOT + r0 + c4) = v;
  }
}

// part[kc][col][row] (f32, [KSPLIT][128][8192]) = raw C partials of
// C = A(f32 [8192][8192]) @ B, B transposed bf16 BT[128][8192].
// A reg->bf16->LDS (XOR swizzle), double-buffered; B direct global->reg.
// One LDS-only barrier per K-step; vmem prefetches live across barriers.
__global__ __launch_bounds__(512, 4) void gemm_part(
    const float* __restrict__ A, const __hip_bfloat16* __restrict__ BTv,
    float* __restrict__ part) {
  constexpr int SZ_A = BM * BK * 2;   // 16 KiB
  __shared__ __align__(16) unsigned char smem[2 * SZ_A];
  const unsigned short* BT = (const unsigned short*)BTv;

  const int bid = blockIdx.x;
  const int kc = (bid & 7) >> 1;                 // XCD-affine K-chunk
  const int mblk = ((bid >> 3) << 1) | (bid & 1);
  const int r0 = mblk * BM;
  const int kbase = kc * KCHUNK;

  const int t = threadIdx.x;
  const int l = t & 63;
  const int w = t >> 6;

  const float* aptr[4];
  int loff_a[4];
#pragma unroll
  for (int r = 0; r < 4; ++r) {
    int idx = t + r * 512;
    int m = idx >> 5, c4 = idx & 31;
    aptr[r] = A + (size_t)(r0 + m) * KTOT + kbase + c4 * 4;
    loff_a[r] = m * 256 + ((c4 * 8) ^ ((m & 7) << 4));
  }

  const int lr = l & 15;
  const int g = l >> 4;
  const int col = w * 16 + lr;
  const unsigned short* bptr = BT + (size_t)col * KTOT + kbase + g * 8;
  const int asw = (lr & 7) << 4;

  f32x4 acc[4];
  const f32x4 fzero = {0.f, 0.f, 0.f, 0.f};
#pragma unroll
  for (int mt = 0; mt < 4; ++mt) acc[mt] = fzero;

  f32x4 av0[4], av1[4];
  bf16x8 Bf0[4], Bf1[4];
  unsigned char* lds0 = smem;
  unsigned char* lds1 = smem + SZ_A;

#define LOAD_A(AV, K0)                                                        \
  _Pragma("unroll") for (int r = 0; r < 4; ++r)                               \
      AV[r] = __builtin_nontemporal_load(                                     \
          reinterpret_cast<const f32x4*>(aptr[r] + (K0)));
#define LOAD_B(BF, K0)                                                        \
  _Pragma("unroll") for (int ks = 0; ks < 4; ++ks)                            \
      BF[ks] = *reinterpret_cast<const bf16x8*>(bptr + (K0) + ks * 32);
#define WRITE_A(LDS, AV)                                                      \
  _Pragma("unroll") for (int r = 0; r < 4; ++r) {                             \
    *reinterpret_cast<uint2*>((LDS) + loff_a[r]) = pack4(AV[r]);              \
  }
#define COMPUTE(LDS, BF)                                                      \
  _Pragma("unroll") for (int ks = 0; ks < 4; ++ks) {                          \
    _Pragma("unroll") for (int mt = 0; mt < 4; ++mt) {                        \
      bf16x8 af_ = *reinterpret_cast<const bf16x8*>(                          \
          (LDS) + (mt * 16 + lr) * 256 + ((ks * 64 + g * 16) ^ asw));         \
      acc[mt] = __builtin_amdgcn_mfma_f32_16x16x32_bf16(af_, BF[ks], acc[mt], \
                                                        0, 0, 0);             \
    }                                                                         \
  }

  // prologue: tiles 0,1 in flight; tile 0 -> lds0
  LOAD_A(av0, 0); LOAD_B(Bf0, 0);
  LOAD_A(av1, BK); LOAD_B(Bf1, BK);
  WRITE_A(lds0, av0);
  block_bar();

#pragma unroll 1
  for (int it = 0; it < NIT; it += 2) {
    // tile it (set 0, lds0)
    if (it + 1 < NIT) { WRITE_A(lds1, av1); }       // av1 = tile it+1
    if (it + 2 < NIT) { LOAD_A(av0, (it + 2) * BK); }
    COMPUTE(lds0, Bf0);
    if (it + 2 < NIT) { LOAD_B(Bf0, (it + 2) * BK); }
    if (it + 1 < NIT) block_bar();
    // tile it+1 (set 1, lds1)
    if (it + 1 < NIT) {
      if (it + 2 < NIT) { WRITE_A(lds0, av0); }     // av0 = tile it+2
      if (it + 3 < NIT) { LOAD_A(av1, (it + 3) * BK); }
      COMPUTE(lds1, Bf1);
      if (it + 3 < NIT) { LOAD_B(Bf1, (it + 3) * BK); }
      if (it + 2 < NIT) block_bar();
    }
  }

  float* pp = part + (size_t)(kc * 128 + col) * KTOT + r0 + g * 4;
#pragma unroll
  for (int mt = 0; mt < 4; ++mt)
    __builtin_nontemporal_store(acc[mt], reinterpret_cast<f32x4*>(pp + mt * 16));
#undef LOAD_A
#undef LOAD_B
#undef WRITE_A
#undef COMPUTE
}

// Combine KSPLIT partials + epilogue, separate halves (lo: cols 0-63, hi: 64-127).
__global__ __launch_bounds__(256) void reduce_sep(
    const float* __restrict__ part, float* __restrict__ out,
    const float* s_lo_p, const float* s_hi_p,
    const float* __restrict__ add_ptr, const float* add_s_p,
    __hip_bfloat16* bt_lo, __hip_bfloat16* bt_hi,
    int base_lo, int base_hi, int accum) {
  const int t = threadIdx.x;
  const int col = t & 127;
  const int rbase = blockIdx.x * 32 + (t >> 7) * 16;
  const float* p0 = part + (size_t)col * KTOT + rbase;
  const bool hi = col >= 64;
  const int col64 = hi ? col - 64 : col;
  __hip_bfloat16* bt = hi ? bt_hi : bt_lo;
  const int obase = hi ? base_hi : base_lo;
  const float s = hi ? (s_hi_p ? *s_hi_p : 0.f) : (s_lo_p ? *s_lo_p : 0.f);
  const float was = add_s_p ? *add_s_p : 0.f;
#pragma unroll
  for (int i = 0; i < 4; ++i) {
    f32x4 c = __builtin_nontemporal_load(
        reinterpret_cast<const f32x4*>(p0 + 4 * i));
#pragma unroll
    for (int k = 1; k < KSPLIT; ++k)
      c += __builtin_nontemporal_load(reinterpret_cast<const f32x4*>(
          p0 + (size_t)k * 128 * KTOT + 4 * i));
    if (bt)
      *reinterpret_cast<uint2*>((unsigned short*)bt + (size_t)col64 * KTOT + rbase + 4 * i) =
          pack4(c);
    if (obase >= 0) {
#pragma unroll
      for (int j = 0; j < 4; ++j) {
        int row = rbase + 4 * i + j;
        float v = s * c[j];
        if (add_ptr && !hi) v = fmaf(was, add_ptr[(size_t)row * 64 + col64], v);
        if (accum) v += out[(size_t)row * 128 + obase + col64];
        out[(size_t)row * 128 + obase + col64] = v;
      }
    }
  }
}

// Combine partials + cross-half epilogue: out[:,64+c] = sl*lo[c] + sh*hi[c];
// bt_lo = raw lo (bf16 transposed).
__global__ __launch_bounds__(256) void reduce_comb(
    const float* __restrict__ part, float* __restrict__ out,
    const float* s_lo_p, const float* s_hi_p, __hip_bfloat16* bt_lo) {
  const int t = threadIdx.x;
  const int c = t & 63;
  const int rbase = blockIdx.x * 32 + (t >> 6) * 8;
  const float* pl = part + (size_t)c * KTOT + rbase;
  const float* ph = part + (size_t)(c + 64) * KTOT + rbase;
  const float sl = *s_lo_p, sh = *s_hi_p;
#pragma unroll
  for (int i = 0; i < 2; ++i) {
    f32x4 lo = __builtin_nontemporal_load(reinterpret_cast<const f32x4*>(pl + 4 * i));
    f32x4 hv = __builtin_nontemporal_load(reinterpret_cast<const f32x4*>(ph + 4 * i));
#pragma unroll
    for (int k = 1; k < KSPLIT; ++k) {
      lo += __builtin_nontemporal_load(reinterpret_cast<const f32x4*>(
          pl + (size_t)k * 128 * KTOT + 4 * i));
      hv += __builtin_nontemporal_load(reinterpret_cast<const f32x4*>(
          ph + (size_t)k * 128 * KTOT + 4 * i));
    }
    *reinterpret_cast<uint2*>((unsigned short*)bt_lo + (size_t)c * KTOT + rbase + 4 * i) =
        pack4(lo);
#pragma unroll
    for (int j = 0; j < 4; ++j) {
      int row = rbase + 4 * i + j;
      out[(size_t)row * 128 + 64 + c] = sl * lo[j] + sh * hv[j];
    }
  }
}

// DIAGNOSTIC: pure A-stream probe replicating the GEMM's exact A access
// pattern (same block mapping, same 512 B/row chunks), 5 passes alternating
// A_p/A_n = 1.34 GB. Runs last; writes 1 MB sink into dead `part` region.
// Its rocprof row reveals the raw achievable BW of this pattern.
__global__ __launch_bounds__(512, 4) void a_probe(
    const float* __restrict__ A0, const float* __restrict__ A1,
    float* __restrict__ sink) {
  const int bid = blockIdx.x;
  const int kc = (bid & 7) >> 1;
  const int mblk = ((bid >> 3) << 1) | (bid & 1);
  const int r0 = mblk * BM;
  const int kbase = kc * KCHUNK;
  const int t = threadIdx.x;
  size_t off[4];
#pragma unroll
  for (int r = 0; r < 4; ++r) {
    int idx = t + r * 512;
    int m = idx >> 5, c4 = idx & 31;
    off[r] = (size_t)(r0 + m) * KTOT + kbase + c4 * 4;
  }
  f32x4 s[4];
#pragma unroll
  for (int r = 0; r < 4; ++r) s[r] = f32x4{0.f, 0.f, 0.f, 0.f};
#pragma unroll 1
  for (int p = 0; p < 5; ++p) {
    const float* A = (p & 1) ? A1 : A0;
#pragma unroll 4
    for (int it = 0; it < NIT; ++it) {
#pragma unroll
      for (int r = 0; r < 4; ++r)
        s[r] += __builtin_nontemporal_load(
            reinterpret_cast<const f32x4*>(A + off[r] + it * BK));
    }
  }
  f32x4 z = s[0] + s[1] + s[2] + s[3];
  sink[(size_t)bid * 512 + t] = z[0] + z[1] + z[2] + z[3];
}

extern "C" void kernel_launch(void* const* d_in, const int* in_sizes, int n_in,
                              void* d_out, int out_size, void* d_ws, size_t ws_size,
                              hipStream_t stream) {
  const float* A_p = (const float*)d_in[0];
  const float* A_n = (const float*)d_in[1];
  const float* x_p = (const float*)d_in[2];
  const float* x_n = (const float*)d_in[3];
  const float* w_p = (const float*)d_in[4];  // [3]
  const float* w_n = (const float*)d_in[5];  // [3]
  float* out = (float*)d_out;                // [8192][128]

  // ws layout (21 MiB):
  //   BTbig [192][8192] bf16: rows 0-63 x_p^T, 64-127 x_n^T, 128-191 Y1^T
  //   B3T   [128][8192] bf16: rows 0-63 P1^T, 64-127 T1^T
  //   part  [KSPLIT][128][8192] f32
  __hip_bfloat16* BTbig = (__hip_bfloat16*)d_ws;
  __hip_bfloat16* B3T = BTbig + (size_t)192 * KTOT;
  float* part = (float*)(B3T + (size_t)128 * KTOT);

  xpose_f32_bf16<<<128, 256, 0, stream>>>(x_p, BTbig);
  xpose_f32_bf16<<<128, 256, 0, stream>>>(x_n, BTbig + (size_t)64 * KTOT);

  // G1: [P1|Y1] = A_p @ [x_p|x_n]
  gemm_part<<<512, 512, 0, stream>>>(A_p, BTbig, part);
  // out[:,0:64] = wp0*x_p + wp1*P1; emit P1^T -> B3T[0:64], Y1^T -> BTbig[128:192]
  reduce_sep<<<256, 256, 0, stream>>>(part, out, w_p + 1, nullptr, x_p, w_p + 0,
                                      B3T, BTbig + (size_t)128 * KTOT, 0, -1, 0);

  // G2': [T1|T3] = A_n @ [x_n|Y1]
  gemm_part<<<512, 512, 0, stream>>>(A_n, BTbig + (size_t)64 * KTOT, part);
  // out[:,64:128] = wn0*T1 + wn2*T3; emit T1^T -> B3T[64:128]
  reduce_comb<<<256, 256, 0, stream>>>(part, out, w_n + 0, w_n + 2,
                                       B3T + (size_t)64 * KTOT);

  // G3: [P2|T2] = A_p @ [P1|T1]
  gemm_part<<<512, 512, 0, stream>>>(A_p, B3T, part);
  // out[:,0:64] += wp2*P2; out[:,64:128] += wn1*T2
  reduce_sep<<<256, 256, 0, stream>>>(part, out, w_p + 2, w_n + 1, nullptr, nullptr,
                                      nullptr, nullptr, 0, 64, 1);

  // DIAGNOSTIC (timed, additive): raw BW of the GEMM's A access pattern.
  a_probe<<<512, 512, 0, stream>>>(A_p, A_n, part);
}

// Round 9
// 238.524 us; speedup vs baseline: 4.0405x; 1.9630x over previous
//
#include <hip/hip_runtime.h>
#include <hip/hip_bf16.h>
#include <stdint.h>

#define KTOT 8192
#define BM 64
#define BK 128
#define KSPLIT 4
#define KCHUNK (KTOT / KSPLIT)   // 2048
#define NIT (KCHUNK / BK)        // 16

typedef __attribute__((ext_vector_type(8))) __bf16 bf16x8;
typedef __attribute__((ext_vector_type(4))) float f32x4;

__device__ __forceinline__ unsigned short f2bf(float f) {
  union { float f; unsigned int u; } a;
  a.f = f;
  unsigned int r = (a.u + 0x7fffu + ((a.u >> 16) & 1u)) >> 16;
  return (unsigned short)r;
}

__device__ __forceinline__ uint2 pack4(f32x4 v) {
  union { unsigned short h[4]; uint2 u; } pk;
  pk.h[0] = f2bf(v[0]); pk.h[1] = f2bf(v[1]);
  pk.h[2] = f2bf(v[2]); pk.h[3] = f2bf(v[3]);
  return pk.u;
}

// Barrier that drains LDS only — global prefetches stay in flight (T4).
__device__ __forceinline__ void block_bar() {
  asm volatile("s_waitcnt lgkmcnt(0)" ::: "memory");
  __builtin_amdgcn_s_barrier();
  __builtin_amdgcn_sched_barrier(0);
}

// x [8192][64] f32  ->  xt [64][8192] bf16 (transposed)
__global__ __launch_bounds__(256) void xpose_f32_bf16(const float* __restrict__ x,
                                                      __hip_bfloat16* __restrict__ xt) {
  __shared__ unsigned short tile[64][72];
  const int r0 = blockIdx.x * 64;
  const int t = threadIdx.x;
  const int a = t >> 4;
  const int c4 = (t & 15) * 4;
#pragma unroll
  for (int rep = 0; rep < 4; ++rep) {
    int r = a + rep * 16;
    f32x4 v = __builtin_nontemporal_load(
        reinterpret_cast<const f32x4*>(x + (size_t)(r0 + r) * 64 + c4));
    tile[c4 + 0][r] = f2bf(v[0]);
    tile[c4 + 1][r] = f2bf(v[1]);
    tile[c4 + 2][r] = f2bf(v[2]);
    tile[c4 + 3][r] = f2bf(v[3]);
  }
  __syncthreads();
#pragma unroll
  for (int rep = 0; rep < 4; ++rep) {
    int j = a + rep * 16;
    uint2 v = *reinterpret_cast<const uint2*>(&tile[j][c4]);
    *reinterpret_cast<uint2*>((unsigned short*)xt + (size_t)j * KTOT + r0 + c4) = v;
  }
}

// part[kc][col][row] (f32, [KSPLIT][128][8192]) = raw C partials of
// C = A(f32 [8192][8192]) @ B, B transposed bf16 BT[128][8192].
// A reg->bf16->LDS (XOR swizzle), double-buffered; B direct global->reg.
// LDS-only barriers (vmem prefetches live across them). Each block's
// K-iteration order is ROTATED by it0 = mblk&15 to de-align the grid-wide
// comb of 512-B row-chunks across HBM channels.
__global__ __launch_bounds__(512, 4) void gemm_part(
    const float* __restrict__ A, const __hip_bfloat16* __restrict__ BTv,
    float* __restrict__ part) {
  constexpr int SZ_A = BM * BK * 2;   // 16 KiB
  __shared__ __align__(16) unsigned char smem[2 * SZ_A];
  const unsigned short* BT = (const unsigned short*)BTv;

  const int bid = blockIdx.x;
  const int kc = (bid & 7) >> 1;                 // XCD-affine K-chunk
  const int mblk = ((bid >> 3) << 1) | (bid & 1);
  const int r0 = mblk * BM;
  const int kbase = kc * KCHUNK;
  const int it0 = mblk & (NIT - 1);              // K-phase rotation

  const int t = threadIdx.x;
  const int l = t & 63;
  const int w = t >> 6;

  const float* aptr[4];
  int loff_a[4];
#pragma unroll
  for (int r = 0; r < 4; ++r) {
    int idx = t + r * 512;
    int m = idx >> 5, c4 = idx & 31;
    aptr[r] = A + (size_t)(r0 + m) * KTOT + kbase + c4 * 4;
    loff_a[r] = m * 256 + ((c4 * 8) ^ ((m & 7) << 4));
  }

  const int lr = l & 15;
  const int g = l >> 4;
  const int col = w * 16 + lr;
  const unsigned short* bptr = BT + (size_t)col * KTOT + kbase + g * 8;
  const int asw = (lr & 7) << 4;

  f32x4 acc[4];
  const f32x4 fzero = {0.f, 0.f, 0.f, 0.f};
#pragma unroll
  for (int mt = 0; mt < 4; ++mt) acc[mt] = fzero;

  f32x4 av0[4], av1[4];
  bf16x8 Bf0[4], Bf1[4];
  unsigned char* lds0 = smem;
  unsigned char* lds1 = smem + SZ_A;

  auto kof = [&](int s) { return ((s + it0) & (NIT - 1)) * BK; };

#define LOAD_A(AV, K0)                                                        \
  _Pragma("unroll") for (int r = 0; r < 4; ++r)                               \
      AV[r] = __builtin_nontemporal_load(                                     \
          reinterpret_cast<const f32x4*>(aptr[r] + (K0)));
#define LOAD_B(BF, K0)                                                        \
  _Pragma("unroll") for (int ks = 0; ks < 4; ++ks)                            \
      BF[ks] = *reinterpret_cast<const bf16x8*>(bptr + (K0) + ks * 32);
#define WRITE_A(LDS, AV)                                                      \
  _Pragma("unroll") for (int r = 0; r < 4; ++r) {                             \
    *reinterpret_cast<uint2*>((LDS) + loff_a[r]) = pack4(AV[r]);              \
  }
#define COMPUTE(LDS, BF)                                                      \
  _Pragma("unroll") for (int ks = 0; ks < 4; ++ks) {                          \
    _Pragma("unroll") for (int mt = 0; mt < 4; ++mt) {                        \
      bf16x8 af_ = *reinterpret_cast<const bf16x8*>(                          \
          (LDS) + (mt * 16 + lr) * 256 + ((ks * 64 + g * 16) ^ asw));         \
      acc[mt] = __builtin_amdgcn_mfma_f32_16x16x32_bf16(af_, BF[ks], acc[mt], \
                                                        0, 0, 0);             \
    }                                                                         \
  }

  // prologue: rotated tiles s=0,1 in flight; s=0 -> lds0
  LOAD_A(av0, kof(0)); LOAD_B(Bf0, kof(0));
  LOAD_A(av1, kof(1)); LOAD_B(Bf1, kof(1));
  WRITE_A(lds0, av0);
  block_bar();

#pragma unroll 1
  for (int s = 0; s < NIT; s += 2) {
    // phase even: rotated tile s (set 0, lds0)
    if (s + 1 < NIT) { WRITE_A(lds1, av1); }        // av1 = tile s+1
    if (s + 2 < NIT) { LOAD_A(av0, kof(s + 2)); }
    COMPUTE(lds0, Bf0);
    if (s + 2 < NIT) { LOAD_B(Bf0, kof(s + 2)); }
    if (s + 1 < NIT) block_bar();
    // phase odd: rotated tile s+1 (set 1, lds1)
    if (s + 1 < NIT) {
      if (s + 2 < NIT) { WRITE_A(lds0, av0); }      // av0 = tile s+2
      if (s + 3 < NIT) { LOAD_A(av1, kof(s + 3)); }
      COMPUTE(lds1, Bf1);
      if (s + 3 < NIT) { LOAD_B(Bf1, kof(s + 3)); }
      if (s + 2 < NIT) block_bar();
    }
  }

  float* pp = part + (size_t)(kc * 128 + col) * KTOT + r0 + g * 4;
#pragma unroll
  for (int mt = 0; mt < 4; ++mt)
    __builtin_nontemporal_store(acc[mt], reinterpret_cast<f32x4*>(pp + mt * 16));
#undef LOAD_A
#undef LOAD_B
#undef WRITE_A
#undef COMPUTE
}

// Combine KSPLIT partials + epilogue, separate halves (lo: cols 0-63, hi: 64-127).
__global__ __launch_bounds__(256) void reduce_sep(
    const float* __restrict__ part, float* __restrict__ out,
    const float* s_lo_p, const float* s_hi_p,
    const float* __restrict__ add_ptr, const float* add_s_p,
    __hip_bfloat16* bt_lo, __hip_bfloat16* bt_hi,
    int base_lo, int base_hi, int accum) {
  const int t = threadIdx.x;
  const int col = t & 127;
  const int rbase = blockIdx.x * 32 + (t >> 7) * 16;
  const float* p0 = part + (size_t)col * KTOT + rbase;
  const bool hi = col >= 64;
  const int col64 = hi ? col - 64 : col;
  __hip_bfloat16* bt = hi ? bt_hi : bt_lo;
  const int obase = hi ? base_hi : base_lo;
  const float s = hi ? (s_hi_p ? *s_hi_p : 0.f) : (s_lo_p ? *s_lo_p : 0.f);
  const float was = add_s_p ? *add_s_p : 0.f;
#pragma unroll
  for (int i = 0; i < 4; ++i) {
    f32x4 c = __builtin_nontemporal_load(
        reinterpret_cast<const f32x4*>(p0 + 4 * i));
#pragma unroll
    for (int k = 1; k < KSPLIT; ++k)
      c += __builtin_nontemporal_load(reinterpret_cast<const f32x4*>(
          p0 + (size_t)k * 128 * KTOT + 4 * i));
    if (bt)
      *reinterpret_cast<uint2*>((unsigned short*)bt + (size_t)col64 * KTOT + rbase + 4 * i) =
          pack4(c);
    if (obase >= 0) {
#pragma unroll
      for (int j = 0; j < 4; ++j) {
        int row = rbase + 4 * i + j;
        float v = s * c[j];
        if (add_ptr && !hi) v = fmaf(was, add_ptr[(size_t)row * 64 + col64], v);
        if (accum) v += out[(size_t)row * 128 + obase + col64];
        out[(size_t)row * 128 + obase + col64] = v;
      }
    }
  }
}

// Combine partials + cross-half epilogue: out[:,64+c] = sl*lo[c] + sh*hi[c];
// bt_lo = raw lo (bf16 transposed).
__global__ __launch_bounds__(256) void reduce_comb(
    const float* __restrict__ part, float* __restrict__ out,
    const float* s_lo_p, const float* s_hi_p, __hip_bfloat16* bt_lo) {
  const int t = threadIdx.x;
  const int c = t & 63;
  const int rbase = blockIdx.x * 32 + (t >> 6) * 8;
  const float* pl = part + (size_t)c * KTOT + rbase;
  const float* ph = part + (size_t)(c + 64) * KTOT + rbase;
  const float sl = *s_lo_p, sh = *s_hi_p;
#pragma unroll
  for (int i = 0; i < 2; ++i) {
    f32x4 lo = __builtin_nontemporal_load(reinterpret_cast<const f32x4*>(pl + 4 * i));
    f32x4 hv = __builtin_nontemporal_load(reinterpret_cast<const f32x4*>(ph + 4 * i));
#pragma unroll
    for (int k = 1; k < KSPLIT; ++k) {
      lo += __builtin_nontemporal_load(reinterpret_cast<const f32x4*>(
          pl + (size_t)k * 128 * KTOT + 4 * i));
      hv += __builtin_nontemporal_load(reinterpret_cast<const f32x4*>(
          ph + (size_t)k * 128 * KTOT + 4 * i));
    }
    *reinterpret_cast<uint2*>((unsigned short*)bt_lo + (size_t)c * KTOT + rbase + 4 * i) =
        pack4(lo);
#pragma unroll
    for (int j = 0; j < 4; ++j) {
      int row = rbase + 4 * i + j;
      out[(size_t)row * 128 + 64 + c] = sl * lo[j] + sh * hv[j];
    }
  }
}

extern "C" void kernel_launch(void* const* d_in, const int* in_sizes, int n_in,
                              void* d_out, int out_size, void* d_ws, size_t ws_size,
                              hipStream_t stream) {
  const float* A_p = (const float*)d_in[0];
  const float* A_n = (const float*)d_in[1];
  const float* x_p = (const float*)d_in[2];
  const float* x_n = (const float*)d_in[3];
  const float* w_p = (const float*)d_in[4];  // [3]
  const float* w_n = (const float*)d_in[5];  // [3]
  float* out = (float*)d_out;                // [8192][128]

  // ws layout (21 MiB):
  //   BTbig [192][8192] bf16: rows 0-63 x_p^T, 64-127 x_n^T, 128-191 Y1^T
  //   B3T   [128][8192] bf16: rows 0-63 P1^T, 64-127 T1^T
  //   part  [KSPLIT][128][8192] f32
  __hip_bfloat16* BTbig = (__hip_bfloat16*)d_ws;
  __hip_bfloat16* B3T = BTbig + (size_t)192 * KTOT;
  float* part = (float*)(B3T + (size_t)128 * KTOT);

  xpose_f32_bf16<<<128, 256, 0, stream>>>(x_p, BTbig);
  xpose_f32_bf16<<<128, 256, 0, stream>>>(x_n, BTbig + (size_t)64 * KTOT);

  // G1: [P1|Y1] = A_p @ [x_p|x_n]
  gemm_part<<<512, 512, 0, stream>>>(A_p, BTbig, part);
  // out[:,0:64] = wp0*x_p + wp1*P1; emit P1^T -> B3T[0:64], Y1^T -> BTbig[128:192]
  reduce_sep<<<256, 256, 0, stream>>>(part, out, w_p + 1, nullptr, x_p, w_p + 0,
                                      B3T, BTbig + (size_t)128 * KTOT, 0, -1, 0);

  // G2': [T1|T3] = A_n @ [x_n|Y1]
  gemm_part<<<512, 512, 0, stream>>>(A_n, BTbig + (size_t)64 * KTOT, part);
  // out[:,64:128] = wn0*T1 + wn2*T3; emit T1^T -> B3T[64:128]
  reduce_comb<<<256, 256, 0, stream>>>(part, out, w_n + 0, w_n + 2,
                                       B3T + (size_t)64 * KTOT);

  // G3: [P2|T2] = A_p @ [P1|T1]
  gemm_part<<<512, 512, 0, stream>>>(A_p, B3T, part);
  // out[:,0:64] += wp2*P2; out[:,64:128] += wn1*T2
  reduce_sep<<<256, 256, 0, stream>>>(part, out, w_p + 2, w_n + 1, nullptr, nullptr,
                                      nullptr, nullptr, 0, 64, 1);
}